// Round 19
// baseline (224.903 us; speedup 1.0000x reference)
//
#include <hip/hip_runtime.h>

#define NB 256      // batch
#define TT 200      // time steps
#define DD 1250     // input dim
#define H1 100
#define H2 20
#define NO 2

// ---- GEMM kernel geometry ----
#define BM 64
#define GRID_A (51200 / BM)   // 800
#define KC 64
#define NCH 20                // 1280 / 64
#define WR 112
#define KPAD 1280
#define PROWS 104             // preT row stride (bf16): 208B, 16B-aligned

// ---- scan geometry ----
#define G 16                  // batches per scan block
#define SCH 4                 // steps per staged chunk
#define SNCHK 50              // 200 / 4
#define HS 136                // H1s/Cs row stride (bf16): 272B -> 2-way banks

typedef __attribute__((ext_vector_type(4))) float f32x4;
typedef __attribute__((ext_vector_type(8))) short s16x8;

__device__ __forceinline__ unsigned short f2bf(float f) {
    unsigned u = __builtin_bit_cast(unsigned, f);
    u += 0x7FFFu + ((u >> 16) & 1u);
    return (unsigned short)(u >> 16);
}
__device__ __forceinline__ float bf2f(unsigned short s) {
    unsigned u = ((unsigned)s) << 16;
    return __builtin_bit_cast(float, u);
}

#define GLL(srcp, dstp) __builtin_amdgcn_global_load_lds( \
    (const __attribute__((address_space(1))) void*)(srcp), \
    (__attribute__((address_space(3))) void*)(dstp), 16, 0, 0)

// LDS-only barrier: gll (vmcnt) stays in flight across steps.
#define STEP_BARRIER() do {                                             \
    asm volatile("s_waitcnt lgkmcnt(0)\n\ts_barrier" ::: "memory");     \
    __builtin_amdgcn_sched_barrier(0);                                  \
} while (0)

// ============ kernel 0: Wih1 fp32 -> bf16 [112][1280] (padded) ===============
__global__ void prep_w(const float* __restrict__ Wih1, unsigned short* __restrict__ w_ws)
{
    const int idx = blockIdx.x * 256 + threadIdx.x;
    if (idx >= WR * KPAD / 4) return;
    const int r  = idx / (KPAD / 4);
    const int k4 = (idx - r * (KPAD / 4)) * 4;
    unsigned short o[4];
    #pragma unroll
    for (int e = 0; e < 4; ++e) {
        const int k = k4 + e;
        o[e] = (r < H1 && k < DD) ? f2bf(Wih1[r * DD + k]) : (unsigned short)0;
    }
    uint2 pk;
    pk.x = (unsigned)o[0] | ((unsigned)o[1] << 16);
    pk.y = (unsigned)o[2] | ((unsigned)o[3] << 16);
    *(uint2*)&w_ws[r * KPAD + k4] = pk;
}

// ============ kernel 1: preT[(b*TT+t)*104 + h] = x@Wih1^T + b1 (bf16) ========
// r16-proven gll staging + swizzle; row stride 104 (16B-aligned for scan gll);
// bias (bih1+bhh1) folded here so the scan skips it.
__launch_bounds__(256, 4)
__global__ void gemm_pre(const float* __restrict__ x,
                         const unsigned short* __restrict__ w_ws,
                         const float* __restrict__ bih1,
                         const float* __restrict__ bhh1,
                         unsigned short* __restrict__ preT)
{
    __shared__ __align__(16) float          a_sf[2][BM * 64];
    __shared__ __align__(16) unsigned short w_sh[2][WR * 64];

    const int tid = threadIdx.x;
    const int bid = blockIdx.x;
    const int wv  = tid >> 6;
    const int ln  = tid & 63;
    const int c16 = ln & 15;
    const int kgrp = ln >> 4;

    f32x4 acc[7];
    #pragma unroll
    for (int i = 0; i < 7; ++i)
        #pragma unroll
        for (int c = 0; c < 4; ++c) acc[i][c] = 0.f;

    float bias[7];
    #pragma unroll
    for (int nt = 0; nt < 7; ++nt) {
        const int col = nt * 16 + c16;
        bias[nt] = (col < H1) ? (bih1[col] + bhh1[col]) : 0.f;
    }

    auto agll = [&](int k0, int buf) {
        #pragma unroll
        for (int q = 0; q < 4; ++q) {
            const int idx  = tid + q * 256;
            const int row  = idx >> 4;
            const int segp = idx & 15;
            const int segl = segp ^ (row & 15);
            const float* src = x + (size_t)(bid * BM + row) * DD + k0 + segl * 4;
            GLL(src, &a_sf[buf][idx * 4]);
        }
    };
    auto wgll = [&](int k0, int buf) {
        #pragma unroll
        for (int q = 0; q < 4; ++q) {
            const int idx = tid + q * 256;
            if (idx < WR * 8) {
                const int row = idx >> 3;
                const int c8p = idx & 7;
                const int c8l = c8p ^ (row & 7);
                const unsigned short* src = w_ws + row * KPAD + k0 + c8l * 8;
                GLL(src, &w_sh[buf][idx * 8]);
            }
        }
    };

    auto mfma_chunk = [&](int buf) {
        #pragma unroll
        for (int s = 0; s < 2; ++s) {
            const int row_a = wv * 16 + c16;
            const int sb = s * 8 + kgrp * 2;
            const int sp0 = (sb + 0) ^ (row_a & 15);
            const int sp1 = (sb + 1) ^ (row_a & 15);
            const float4 av0 = *(const float4*)&a_sf[buf][row_a * 64 + sp0 * 4];
            const float4 av1 = *(const float4*)&a_sf[buf][row_a * 64 + sp1 * 4];
            const s16x8 af = {
                (short)f2bf(av0.x), (short)f2bf(av0.y),
                (short)f2bf(av0.z), (short)f2bf(av0.w),
                (short)f2bf(av1.x), (short)f2bf(av1.y),
                (short)f2bf(av1.z), (short)f2bf(av1.w) };
            #pragma unroll
            for (int nt = 0; nt < 7; ++nt) {
                const int row_b = nt * 16 + c16;
                const int c8  = s * 4 + kgrp;
                const int c8p = c8 ^ (row_b & 7);
                const s16x8 bf = *(const s16x8*)&w_sh[buf][row_b * 64 + c8p * 8];
                acc[nt] = __builtin_amdgcn_mfma_f32_16x16x32_bf16(af, bf, acc[nt], 0, 0, 0);
            }
        }
    };

    float4 ta[4];
    #pragma unroll
    for (int q = 0; q < 4; ++q) {
        const int idx  = tid + q * 256;
        const int row  = idx >> 4;
        const int segl = idx & 15;
        const int gk   = 19 * KC + segl * 4;
        const float* xp = x + (size_t)(bid * BM + row) * DD + gk;
        float4 v;
        v.x = (gk + 0 < DD) ? xp[0] : 0.f;
        v.y = (gk + 1 < DD) ? xp[1] : 0.f;
        v.z = (gk + 2 < DD) ? xp[2] : 0.f;
        v.w = (gk + 3 < DD) ? xp[3] : 0.f;
        ta[q] = v;
    }

    agll(0, 0);
    wgll(0, 0);

    for (int kc = 0; kc < 19; ++kc) {
        const int buf = kc & 1;
        __syncthreads();
        if (kc + 1 < 19) agll((kc + 1) * KC, buf ^ 1);
        wgll((kc + 1) * KC, buf ^ 1);
        mfma_chunk(buf);
    }

    #pragma unroll
    for (int q = 0; q < 4; ++q) {
        const int idx  = tid + q * 256;
        const int row  = idx >> 4;
        const int segl = idx & 15;
        const int sp   = segl ^ (row & 15);
        *(float4*)&a_sf[1][row * 64 + sp * 4] = ta[q];
    }
    __syncthreads();
    mfma_chunk(1);

    // C/D: col = l&15, row = (l>>4)*4 + reg (m89-verified). Bias folded here.
    const int rg = bid * BM + wv * 16 + (kgrp << 2);
    #pragma unroll
    for (int nt = 0; nt < 7; ++nt) {
        const int col = nt * 16 + c16;
        if (col < H1) {
            #pragma unroll
            for (int r = 0; r < 4; ++r)
                preT[(size_t)(rg + r) * PROWS + col] = f2bf(acc[nt][r] + bias[nt]);
        }
    }
}

// ============ kernel 2: MFMA-batched two-layer scan + FC =====================
// G=16 batches/block (16 blocks). Per step: H1n[100x16] = relu(W1 @ H1 + pre),
// o1 = H1n*mask; layer2 (wave 3) h2 = relu([Wih2|Whh2] @ [o1|h2]) one step
// behind. W fragments live in registers (A-operand); per-step LDS is ~50 wide
// ops for 16 batches (vs 67/batch in the VALU scan). pre/mask gll-staged in
// 4-step chunks; fenceless in-chunk barriers keep gll in flight.
__launch_bounds__(256, 1)
__global__ void scan_rnn(const unsigned short* __restrict__ preT,
                         const float* __restrict__ Whh1,
                         const float* __restrict__ Wih2,
                         const float* __restrict__ Whh2,
                         const float* __restrict__ bih2,
                         const float* __restrict__ bhh2,
                         const float* __restrict__ Wfc,
                         const float* __restrict__ bfc,
                         const float* __restrict__ mask1,
                         const float* __restrict__ mask2,
                         float* __restrict__ out)
{
    __shared__ __align__(16) unsigned short H1s[2][G * HS];      // h1 (unmasked)
    __shared__ __align__(16) unsigned short Cs [2][G * HS];      // [o1|h2|0]
    __shared__ __align__(16) unsigned short PREs[2][SCH * G * PROWS];
    __shared__ __align__(16) float MASKs[2][SCH * G * H1];

    const int tid = threadIdx.x;
    const int b0  = blockIdx.x * G;
    const int wv  = tid >> 6;
    const int ln  = tid & 63;
    const int g   = ln & 15;          // batch (B col / C col)
    const int ro  = ln >> 4;          // 0..3

    // ---- A-fragments (one-time). Layouts proven in gemm_pre. ----
    s16x8 a1f[2][4] = {};
    #pragma unroll
    for (int ti = 0; ti < 2; ++ti) {
        const int rt = 2 * wv + ti;
        if (rt < 7) {
            const int row = rt * 16 + g;
            #pragma unroll
            for (int kt = 0; kt < 4; ++kt) {
                const int kb = kt * 32 + ro * 8;
                s16x8 f = {};
                if (row < H1) {
                    #pragma unroll
                    for (int j = 0; j < 8; ++j) {
                        const int k = kb + j;
                        const float v = (k < H1) ? Whh1[row * H1 + k] : 0.f;
                        f[j] = (short)f2bf(v);
                    }
                }
                a1f[ti][kt] = f;
            }
        }
    }
    s16x8 a2f[2][4] = {};
    f32x4 b2v[2] = {};
    if (wv == 3) {
        #pragma unroll
        for (int ti = 0; ti < 2; ++ti) {
            const int row = ti * 16 + g;
            #pragma unroll
            for (int kt = 0; kt < 4; ++kt) {
                const int kb = kt * 32 + ro * 8;
                s16x8 f = {};
                if (row < H2) {
                    #pragma unroll
                    for (int j = 0; j < 8; ++j) {
                        const int k = kb + j;
                        float v = 0.f;
                        if (k < H1) v = Wih2[row * H1 + k];
                        else if (k < H1 + H2) v = Whh2[row * H2 + (k - H1)];
                        f[j] = (short)f2bf(v);
                    }
                }
                a2f[ti][kt] = f;
            }
            const int rb2 = ti * 16 + ro * 4;
            #pragma unroll
            for (int r = 0; r < 4; ++r)
                b2v[ti][r] = (rb2 + r < H2) ? (bih2[rb2 + r] + bhh2[rb2 + r]) : 0.f;
        }
    }

    for (int i = tid; i < G * HS; i += 256) {       // zero states (both dbufs)
        H1s[0][i] = 0; H1s[1][i] = 0; Cs[0][i] = 0; Cs[1][i] = 0;
    }

    // gll stagers: wave-linear dests (slot = tid + i*256)
    auto stage = [&](int c, int pb) {
        for (int s = tid; s < SCH * G * 13; s += 256) {      // pre: 13x16B/row
            const int ug = s / 13, ss = s - ug * 13;
            const int u = ug >> 4, gg = ug & 15;
            const unsigned short* src = preT +
                ((size_t)(b0 + gg) * TT + (c * SCH + u)) * PROWS + ss * 8;
            GLL(src, &PREs[pb][s * 8]);
        }
        for (int s = tid; s < SCH * G * 25; s += 256) {      // mask: 25x16B/row
            const int ug = s / 25, ss = s - ug * 25;
            const int u = ug >> 4, gg = ug & 15;
            const float* src = mask1 +
                ((size_t)(b0 + gg) * TT + (c * SCH + u)) * H1 + ss * 4;
            GLL(src, &MASKs[pb][s * 4]);
        }
    };

    stage(0, 0);
    __syncthreads();

    for (int c = 0; c < SNCHK; ++c) {
        const int pb = c & 1;
        #pragma unroll
        for (int u = 0; u < SCH; ++u) {
            const int t = c * SCH + u;
            const int cur = t & 1, nxt = cur ^ 1;
            if (u > 0) STEP_BARRIER();
            if (u == 0 && c + 1 < SNCHK) stage(c + 1, pb ^ 1);

            // ---- layer1 ----
            s16x8 bfr[4];
            #pragma unroll
            for (int kt = 0; kt < 4; ++kt)
                bfr[kt] = *(const s16x8*)&H1s[cur][g * HS + kt * 32 + ro * 8];

            #pragma unroll
            for (int ti = 0; ti < 2; ++ti) {
                const int rt = 2 * wv + ti;
                if (rt < 7) {
                    f32x4 acc = {0.f, 0.f, 0.f, 0.f};
                    #pragma unroll
                    for (int kt = 0; kt < 4; ++kt)
                        acc = __builtin_amdgcn_mfma_f32_16x16x32_bf16(
                            a1f[ti][kt], bfr[kt], acc, 0, 0, 0);
                    const int rb = rt * 16 + ro * 4;
                    const uint2 pr = *(const uint2*)&PREs[pb][(u * 16 + g) * PROWS + rb];
                    const float4 mk = *(const float4*)&MASKs[pb][(u * 16 + g) * H1 + rb];
                    const float v0 = fmaxf(acc[0] + bf2f((unsigned short)(pr.x)), 0.f);
                    const float v1 = fmaxf(acc[1] + bf2f((unsigned short)(pr.x >> 16)), 0.f);
                    const float v2 = fmaxf(acc[2] + bf2f((unsigned short)(pr.y)), 0.f);
                    const float v3 = fmaxf(acc[3] + bf2f((unsigned short)(pr.y >> 16)), 0.f);
                    if (rb < H1) {
                        uint2 hw, ow;
                        hw.x = (unsigned)f2bf(v0) | ((unsigned)f2bf(v1) << 16);
                        hw.y = (unsigned)f2bf(v2) | ((unsigned)f2bf(v3) << 16);
                        ow.x = (unsigned)f2bf(v0 * mk.x) | ((unsigned)f2bf(v1 * mk.y) << 16);
                        ow.y = (unsigned)f2bf(v2 * mk.z) | ((unsigned)f2bf(v3 * mk.w) << 16);
                        *(uint2*)&H1s[nxt][g * HS + rb] = hw;
                        *(uint2*)&Cs[nxt][g * HS + rb] = ow;
                    }
                }
            }

            // ---- layer2 (wave 3): h2(t-1) from o1(t-1), h2(t-2) ----
            if (wv == 3 && t >= 1) {
                s16x8 cfr[4];
                #pragma unroll
                for (int kt = 0; kt < 4; ++kt)
                    cfr[kt] = *(const s16x8*)&Cs[cur][g * HS + kt * 32 + ro * 8];
                #pragma unroll
                for (int ti = 0; ti < 2; ++ti) {
                    f32x4 acc = {0.f, 0.f, 0.f, 0.f};
                    #pragma unroll
                    for (int kt = 0; kt < 4; ++kt)
                        acc = __builtin_amdgcn_mfma_f32_16x16x32_bf16(
                            a2f[ti][kt], cfr[kt], acc, 0, 0, 0);
                    const int rb = ti * 16 + ro * 4;
                    if (rb < H2) {
                        const float v0 = fmaxf(acc[0] + b2v[ti][0], 0.f);
                        const float v1 = fmaxf(acc[1] + b2v[ti][1], 0.f);
                        const float v2 = fmaxf(acc[2] + b2v[ti][2], 0.f);
                        const float v3 = fmaxf(acc[3] + b2v[ti][3], 0.f);
                        uint2 w2;
                        w2.x = (unsigned)f2bf(v0) | ((unsigned)f2bf(v1) << 16);
                        w2.y = (unsigned)f2bf(v2) | ((unsigned)f2bf(v3) << 16);
                        *(uint2*)&Cs[nxt][g * HS + H1 + rb] = w2;
                    }
                }
            }
        }
        __syncthreads();               // drains gll; publishes chunk
    }

    // epilogue "t=200": h2(199) from Cs[0] -> Cs[1]
    if (wv == 3) {
        s16x8 cfr[4];
        #pragma unroll
        for (int kt = 0; kt < 4; ++kt)
            cfr[kt] = *(const s16x8*)&Cs[0][g * HS + kt * 32 + ro * 8];
        #pragma unroll
        for (int ti = 0; ti < 2; ++ti) {
            f32x4 acc = {0.f, 0.f, 0.f, 0.f};
            #pragma unroll
            for (int kt = 0; kt < 4; ++kt)
                acc = __builtin_amdgcn_mfma_f32_16x16x32_bf16(
                    a2f[ti][kt], cfr[kt], acc, 0, 0, 0);
            const int rb = ti * 16 + ro * 4;
            if (rb < H2) {
                const float v0 = fmaxf(acc[0] + b2v[ti][0], 0.f);
                const float v1 = fmaxf(acc[1] + b2v[ti][1], 0.f);
                const float v2 = fmaxf(acc[2] + b2v[ti][2], 0.f);
                const float v3 = fmaxf(acc[3] + b2v[ti][3], 0.f);
                uint2 w2;
                w2.x = (unsigned)f2bf(v0) | ((unsigned)f2bf(v1) << 16);
                w2.y = (unsigned)f2bf(v2) | ((unsigned)f2bf(v3) << 16);
                *(uint2*)&Cs[1][g * HS + H1 + rb] = w2;
            }
        }
    }
    __syncthreads();

    // FC on h2(199) (in Cs[1]) with mask2[:,199,:]
    if (tid < G * NO) {
        const int bb = tid >> 1, o = tid & 1;
        float s = bfc[o];
        #pragma unroll
        for (int k = 0; k < H2; ++k) {
            const float h2k = bf2f(Cs[1][bb * HS + H1 + k]);
            const float m2k = mask2[((size_t)(b0 + bb) * TT + (TT - 1)) * H2 + k];
            s = fmaf(Wfc[o * H2 + k], h2k * m2k, s);
        }
        out[(b0 + bb) * NO + o] = s;
    }
}

extern "C" void kernel_launch(void* const* d_in, const int* in_sizes, int n_in,
                              void* d_out, int out_size, void* d_ws, size_t ws_size,
                              hipStream_t stream) {
    const float* x     = (const float*)d_in[0];
    const float* Wih1  = (const float*)d_in[1];
    const float* Whh1  = (const float*)d_in[2];
    const float* bih1  = (const float*)d_in[3];
    const float* bhh1  = (const float*)d_in[4];
    const float* Wih2  = (const float*)d_in[5];
    const float* Whh2  = (const float*)d_in[6];
    const float* bih2  = (const float*)d_in[7];
    const float* bhh2  = (const float*)d_in[8];
    const float* Wfc   = (const float*)d_in[9];
    const float* bfc   = (const float*)d_in[10];
    const float* mask1 = (const float*)d_in[11];
    const float* mask2 = (const float*)d_in[12];
    float* out = (float*)d_out;

    unsigned short* preT = (unsigned short*)d_ws;                     // 10,649,600 B
    unsigned short* w_ws = (unsigned short*)((char*)d_ws + 10649600); //    286,720 B

    prep_w  <<<dim3((WR * KPAD / 4 + 255) / 256), dim3(256), 0, stream>>>(Wih1, w_ws);
    gemm_pre<<<dim3(GRID_A), dim3(256), 0, stream>>>(x, w_ws, bih1, bhh1, preT);
    scan_rnn<<<dim3(NB / G), dim3(256), 0, stream>>>(preT, Whh1, Wih2, Whh2,
                                                     bih2, bhh2, Wfc, bfc,
                                                     mask1, mask2, out);
}

// Round 21
// 177.914 us; speedup vs baseline: 1.2641x; 1.2641x over previous
//
#include <hip/hip_runtime.h>

#define NB 256      // batch
#define TT 200      // time steps
#define DD 1250     // input dim
#define H1 100
#define H2 20
#define NO 2

// ---- GEMM kernel geometry ----
#define BM 64
#define GRID_A (51200 / BM)   // 800
#define KC 64
#define NCH 20                // 1280 / 64
#define WR 112
#define KPAD 1280

// ---- scan geometry ----
#define CH 8                  // steps per staged chunk
#define NCHK 25               // 200 / 8

typedef __attribute__((ext_vector_type(4))) float f32x4;
typedef __attribute__((ext_vector_type(8))) short s16x8;

__device__ __forceinline__ unsigned short f2bf(float f) {
    unsigned u = __builtin_bit_cast(unsigned, f);
    u += 0x7FFFu + ((u >> 16) & 1u);
    return (unsigned short)(u >> 16);
}
__device__ __forceinline__ float bf2f(unsigned short s) {
    unsigned u = ((unsigned)s) << 16;
    return __builtin_bit_cast(float, u);
}
__device__ __forceinline__ float bflo(unsigned u) {
    return __builtin_bit_cast(float, u << 16);
}
__device__ __forceinline__ float bfhi(unsigned u) {
    return __builtin_bit_cast(float, u & 0xffff0000u);
}

#define GLL(srcp, dstp) __builtin_amdgcn_global_load_lds( \
    (const __attribute__((address_space(1))) void*)(srcp), \
    (__attribute__((address_space(3))) void*)(dstp), 16, 0, 0)

// LDS-only barrier (r18-proven): global loads stay in flight across steps.
#define STEP_BARRIER() do {                                             \
    asm volatile("s_waitcnt lgkmcnt(0)\n\ts_barrier" ::: "memory");     \
    __builtin_amdgcn_sched_barrier(0);                                  \
} while (0)

// ============ kernel 0: Wih1 fp32 -> bf16 [112][1280] (padded) ===============
__global__ void prep_w(const float* __restrict__ Wih1, unsigned short* __restrict__ w_ws)
{
    const int idx = blockIdx.x * 256 + threadIdx.x;
    if (idx >= WR * KPAD / 4) return;
    const int r  = idx / (KPAD / 4);
    const int k4 = (idx - r * (KPAD / 4)) * 4;
    unsigned short o[4];
    #pragma unroll
    for (int e = 0; e < 4; ++e) {
        const int k = k4 + e;
        o[e] = (r < H1 && k < DD) ? f2bf(Wih1[r * DD + k]) : (unsigned short)0;
    }
    uint2 pk;
    pk.x = (unsigned)o[0] | ((unsigned)o[1] << 16);
    pk.y = (unsigned)o[2] | ((unsigned)o[3] << 16);
    *(uint2*)&w_ws[r * KPAD + k4] = pk;
}

// ============ kernel 1: pre1[(b*TT+t)*H1 + h] (bf16) — r16/r18 exact =========
__launch_bounds__(256, 4)
__global__ void gemm_pre(const float* __restrict__ x,
                         const unsigned short* __restrict__ w_ws,
                         unsigned short* __restrict__ preT)
{
    __shared__ __align__(16) float          a_sf[2][BM * 64];
    __shared__ __align__(16) unsigned short w_sh[2][WR * 64];

    const int tid = threadIdx.x;
    const int bid = blockIdx.x;
    const int wv  = tid >> 6;
    const int ln  = tid & 63;
    const int c16 = ln & 15;
    const int kgrp = ln >> 4;

    f32x4 acc[7];
    #pragma unroll
    for (int i = 0; i < 7; ++i)
        #pragma unroll
        for (int c = 0; c < 4; ++c) acc[i][c] = 0.f;

    auto agll = [&](int k0, int buf) {
        #pragma unroll
        for (int q = 0; q < 4; ++q) {
            const int idx  = tid + q * 256;
            const int row  = idx >> 4;
            const int segp = idx & 15;
            const int segl = segp ^ (row & 15);
            const float* src = x + (size_t)(bid * BM + row) * DD + k0 + segl * 4;
            GLL(src, &a_sf[buf][idx * 4]);
        }
    };
    auto wgll = [&](int k0, int buf) {
        #pragma unroll
        for (int q = 0; q < 4; ++q) {
            const int idx = tid + q * 256;
            if (idx < WR * 8) {
                const int row = idx >> 3;
                const int c8p = idx & 7;
                const int c8l = c8p ^ (row & 7);
                const unsigned short* src = w_ws + row * KPAD + k0 + c8l * 8;
                GLL(src, &w_sh[buf][idx * 8]);
            }
        }
    };

    auto mfma_chunk = [&](int buf) {
        #pragma unroll
        for (int s = 0; s < 2; ++s) {
            const int row_a = wv * 16 + c16;
            const int sb = s * 8 + kgrp * 2;
            const int sp0 = (sb + 0) ^ (row_a & 15);
            const int sp1 = (sb + 1) ^ (row_a & 15);
            const float4 av0 = *(const float4*)&a_sf[buf][row_a * 64 + sp0 * 4];
            const float4 av1 = *(const float4*)&a_sf[buf][row_a * 64 + sp1 * 4];
            const s16x8 af = {
                (short)f2bf(av0.x), (short)f2bf(av0.y),
                (short)f2bf(av0.z), (short)f2bf(av0.w),
                (short)f2bf(av1.x), (short)f2bf(av1.y),
                (short)f2bf(av1.z), (short)f2bf(av1.w) };
            #pragma unroll
            for (int nt = 0; nt < 7; ++nt) {
                const int row_b = nt * 16 + c16;
                const int c8  = s * 4 + kgrp;
                const int c8p = c8 ^ (row_b & 7);
                const s16x8 bf = *(const s16x8*)&w_sh[buf][row_b * 64 + c8p * 8];
                acc[nt] = __builtin_amdgcn_mfma_f32_16x16x32_bf16(af, bf, acc[nt], 0, 0, 0);
            }
        }
    };

    float4 ta[4];
    #pragma unroll
    for (int q = 0; q < 4; ++q) {
        const int idx  = tid + q * 256;
        const int row  = idx >> 4;
        const int segl = idx & 15;
        const int gk   = 19 * KC + segl * 4;
        const float* xp = x + (size_t)(bid * BM + row) * DD + gk;
        float4 v;
        v.x = (gk + 0 < DD) ? xp[0] : 0.f;
        v.y = (gk + 1 < DD) ? xp[1] : 0.f;
        v.z = (gk + 2 < DD) ? xp[2] : 0.f;
        v.w = (gk + 3 < DD) ? xp[3] : 0.f;
        ta[q] = v;
    }

    agll(0, 0);
    wgll(0, 0);

    for (int kc = 0; kc < 19; ++kc) {
        const int buf = kc & 1;
        __syncthreads();
        if (kc + 1 < 19) agll((kc + 1) * KC, buf ^ 1);
        wgll((kc + 1) * KC, buf ^ 1);
        mfma_chunk(buf);
    }

    #pragma unroll
    for (int q = 0; q < 4; ++q) {
        const int idx  = tid + q * 256;
        const int row  = idx >> 4;
        const int segl = idx & 15;
        const int sp   = segl ^ (row & 15);
        *(float4*)&a_sf[1][row * 64 + sp * 4] = ta[q];
    }
    __syncthreads();
    mfma_chunk(1);

    const int rg = bid * BM + wv * 16 + (kgrp << 2);
    #pragma unroll
    for (int nt = 0; nt < 7; ++nt) {
        const int col = nt * 16 + c16;
        if (col < H1) {
            #pragma unroll
            for (int r = 0; r < 4; ++r)
                preT[(size_t)(rg + r) * H1 + col] = f2bf(acc[nt][r]);
        }
    }
}

// ============ kernel 2: scan + FC — r18 structure, bf16 STATE ================
// r17 decomposition: dot cost ~860cy/step == LDS-pipe instr stream (~68 wide
// ops x ~12cy). bf16 state halves the h-vector reads: 7 uint4/thread (16B-
// aligned windows: l1 p*48 (56 elems), l2 p3*56 (64 elems); overlaps carry
// ZERO weights). Unpack = verified bit-ops (u<<16 / u&0xffff0000), no asm.
// Weights stay f32 in named float4s (r18-proven). r19 validated bf16-state
// numerics end-to-end (absmax 0.03125).
#define UFMA(W, U0, U1) {                                                   \
    a0 = fmaf((W).x, bflo(U0), a0); a1 = fmaf((W).y, bfhi(U0), a1);         \
    a2 = fmaf((W).z, bflo(U1), a2); a3 = fmaf((W).w, bfhi(U1), a3); }

__launch_bounds__(320, 1)
__global__ void scan_rnn(const unsigned short* __restrict__ preT,
                         const float* __restrict__ Whh1,
                         const float* __restrict__ bih1,
                         const float* __restrict__ bhh1,
                         const float* __restrict__ Wih2,
                         const float* __restrict__ Whh2,
                         const float* __restrict__ bih2,
                         const float* __restrict__ bhh2,
                         const float* __restrict__ Wfc,
                         const float* __restrict__ bfc,
                         const float* __restrict__ mask1,
                         const float* __restrict__ mask2,
                         float* __restrict__ out)
{
    __shared__ __align__(16) unsigned short h1_bf[2][112];  // h1(t); [100..111]=0
    __shared__ __align__(16) unsigned short c_bf[2][128];   // [o1|h2|pad0]
    __shared__ alignas(16) float h2f_s[H2];
    __shared__ alignas(16) float m_lds[2][CH * H1];         // mask1 chunks (f32)
    __shared__ alignas(16) float p_lds[2][CH * H1];         // pre1 chunks (f32)

    const int tid = threadIdx.x;
    const int b   = blockIdx.x;
    const float* m1b = mask1 + (size_t)b * TT * H1;
    const unsigned short* pTb = preT + (size_t)b * TT * H1;

    const int h = tid >> 1;
    const int p = tid & 1;
    const bool l1t = (tid < 200);
    const bool l2t = (tid >= 256 && tid < 256 + 2 * H2);    // wave 4 only
    const int k2 = (tid - 256) >> 1;
    const int p3 = (tid - 256) & 1;

    // named f32 weights: l1 uses w00..w13 (56 slots), l2 uses w00..w15 (64)
    float4 w00{}, w01{}, w02{}, w03{}, w04{}, w05{}, w06{}, w07{},
           w08{}, w09{}, w10{}, w11{}, w12{}, w13{}, w14{}, w15{};
    float b1 = 0.f;

    if (l1t) {
        // window [p*48 .. p*48+55]; zero weights on overlap/pad:
        // p=0: w00..w12 = Whh1[h][0..51], w13 = 0
        // p=1: w00 = 0, w01..w12 = Whh1[h][52..99], w13 = 0
        const float* wr = Whh1 + h * H1 + p * 48;
        if (p == 0) w00 = *(const float4*)(wr + 0);
        w01 = *(const float4*)(wr +  4); w02 = *(const float4*)(wr +  8);
        w03 = *(const float4*)(wr + 12); w04 = *(const float4*)(wr + 16);
        w05 = *(const float4*)(wr + 20); w06 = *(const float4*)(wr + 24);
        w07 = *(const float4*)(wr + 28); w08 = *(const float4*)(wr + 32);
        w09 = *(const float4*)(wr + 36); w10 = *(const float4*)(wr + 40);
        w11 = *(const float4*)(wr + 44); w12 = *(const float4*)(wr + 48);
        if (p == 0) b1 = bih1[h] + bhh1[h];
    } else if (l2t) {
        // input vec [o1(0..99) | h2(100..119)]; window [p3*56 .. p3*56+63]
        if (p3 == 0) {
            const float* wi = Wih2 + k2 * H1;               // idx 0..63
            w00 = *(const float4*)(wi +  0); w01 = *(const float4*)(wi +  4);
            w02 = *(const float4*)(wi +  8); w03 = *(const float4*)(wi + 12);
            w04 = *(const float4*)(wi + 16); w05 = *(const float4*)(wi + 20);
            w06 = *(const float4*)(wi + 24); w07 = *(const float4*)(wi + 28);
            w08 = *(const float4*)(wi + 32); w09 = *(const float4*)(wi + 36);
            w10 = *(const float4*)(wi + 40); w11 = *(const float4*)(wi + 44);
            w12 = *(const float4*)(wi + 48); w13 = *(const float4*)(wi + 52);
            w14 = *(const float4*)(wi + 56); w15 = *(const float4*)(wi + 60);
            b1 = bih2[k2] + bhh2[k2];                       // b2 in b1 slot
        } else {
            // idx 56..119: w00,w01 = 0 (56..63 owned by p3=0);
            // w02..w10 = Wih2[64..99]; w11..w15 = Whh2[0..19]
            const float* wi = Wih2 + k2 * H1;
            w02 = *(const float4*)(wi + 64); w03 = *(const float4*)(wi + 68);
            w04 = *(const float4*)(wi + 72); w05 = *(const float4*)(wi + 76);
            w06 = *(const float4*)(wi + 80); w07 = *(const float4*)(wi + 84);
            w08 = *(const float4*)(wi + 88); w09 = *(const float4*)(wi + 92);
            w10 = *(const float4*)(wi + 96);
            const float* wh = Whh2 + k2 * H2;
            w11 = *(const float4*)(wh +  0); w12 = *(const float4*)(wh +  4);
            w13 = *(const float4*)(wh +  8); w14 = *(const float4*)(wh + 12);
            w15 = *(const float4*)(wh + 16);
        }
    }

    for (int i = tid; i < 112; i += 320) { h1_bf[0][i] = 0; h1_bf[1][i] = 0; }
    for (int i = tid; i < 128; i += 320) { c_bf[0][i] = 0;  c_bf[1][i] = 0; }

    // stage chunk 0 into buffer 0 (t = 0..7): one wide load per thread
    if (tid < 200) {
        const float4 mv = *(const float4*)&m1b[tid * 4];
        *(float4*)&m_lds[0][tid * 4] = mv;
    } else if (tid < 300) {
        const s16x8 pv = *(const s16x8*)&pTb[(tid - 200) * 8];
        float* dst = &p_lds[0][(tid - 200) * 8];
        *(float4*)dst       = make_float4(bf2f(pv[0]), bf2f(pv[1]), bf2f(pv[2]), bf2f(pv[3]));
        *(float4*)(dst + 4) = make_float4(bf2f(pv[4]), bf2f(pv[5]), bf2f(pv[6]), bf2f(pv[7]));
    }
    __syncthreads();

    int buf = 0;
    for (int c = 0; c < NCHK; ++c) {
        const bool more = (c + 1 < NCHK);
        float4 mst{}; s16x8 pst{};

        #pragma unroll
        for (int u = 0; u < CH; ++u) {
            const int t = c * CH + u;
            const int cur = t & 1, nxt = cur ^ 1;

            if (u > 0) STEP_BARRIER();         // LDS-only sync; no vmcnt drain

            if (u == 0 && more) {              // issue next chunk's loads
                const int base = (c + 1) * (CH * H1);
                if (tid < 200)      mst = *(const float4*)&m1b[base + tid * 4];
                else if (tid < 300) pst = *(const s16x8*)&pTb[base + (tid - 200) * 8];
            }

            if (l1t) {
                float a0 = (p == 0) ? (p_lds[buf][u * H1 + h] + b1) : 0.f;
                const float mv = (p == 1) ? m_lds[buf][u * H1 + h] : 0.f;
                float a1 = 0.f, a2 = 0.f, a3 = 0.f;
                const unsigned short* hb = &h1_bf[cur][p * 48];
                const uint4 u0 = *(const uint4*)(hb +  0);
                const uint4 u1 = *(const uint4*)(hb +  8);
                const uint4 u2 = *(const uint4*)(hb + 16);
                const uint4 u3 = *(const uint4*)(hb + 24);
                const uint4 u4 = *(const uint4*)(hb + 32);
                const uint4 u5 = *(const uint4*)(hb + 40);
                const uint4 u6 = *(const uint4*)(hb + 48);
                UFMA(w00, u0.x, u0.y); UFMA(w01, u0.z, u0.w);
                UFMA(w02, u1.x, u1.y); UFMA(w03, u1.z, u1.w);
                UFMA(w04, u2.x, u2.y); UFMA(w05, u2.z, u2.w);
                UFMA(w06, u3.x, u3.y); UFMA(w07, u3.z, u3.w);
                UFMA(w08, u4.x, u4.y); UFMA(w09, u4.z, u4.w);
                UFMA(w10, u5.x, u5.y); UFMA(w11, u5.z, u5.w);
                UFMA(w12, u6.x, u6.y); UFMA(w13, u6.z, u6.w);
                float part = (a0 + a1) + (a2 + a3);
                float tot  = part + __shfl_xor(part, 1);
                tot = fmaxf(tot, 0.f);                       // h1(t)
                if (p == 0) h1_bf[nxt][h] = f2bf(tot);
                else        c_bf[nxt][h]  = f2bf(tot * mv);  // o1(t)
            }

            if (l2t && t >= 1) {
                float a0 = (p3 == 0) ? b1 : 0.f;
                float a1 = 0.f, a2 = 0.f, a3 = 0.f;
                const unsigned short* cb = &c_bf[cur][p3 * 56];
                const uint4 u0 = *(const uint4*)(cb +  0);
                const uint4 u1 = *(const uint4*)(cb +  8);
                const uint4 u2 = *(const uint4*)(cb + 16);
                const uint4 u3 = *(const uint4*)(cb + 24);
                const uint4 u4 = *(const uint4*)(cb + 32);
                const uint4 u5 = *(const uint4*)(cb + 40);
                const uint4 u6 = *(const uint4*)(cb + 48);
                const uint4 u7 = *(const uint4*)(cb + 56);
                UFMA(w00, u0.x, u0.y); UFMA(w01, u0.z, u0.w);
                UFMA(w02, u1.x, u1.y); UFMA(w03, u1.z, u1.w);
                UFMA(w04, u2.x, u2.y); UFMA(w05, u2.z, u2.w);
                UFMA(w06, u3.x, u3.y); UFMA(w07, u3.z, u3.w);
                UFMA(w08, u4.x, u4.y); UFMA(w09, u4.z, u4.w);
                UFMA(w10, u5.x, u5.y); UFMA(w11, u5.z, u5.w);
                UFMA(w12, u6.x, u6.y); UFMA(w13, u6.z, u6.w);
                UFMA(w14, u7.x, u7.y); UFMA(w15, u7.z, u7.w);
                float part = (a0 + a1) + (a2 + a3);
                part += __shfl_xor(part, 1);
                const float h2v = fmaxf(part, 0.f);          // h2(t-1)
                if (p3 == 0) c_bf[nxt][H1 + k2] = f2bf(h2v);
            }
        }

        if (more) {                            // publish staged chunk
            if (tid < 200) {
                *(float4*)&m_lds[buf ^ 1][tid * 4] = mst;
            } else if (tid < 300) {
                float* dst = &p_lds[buf ^ 1][(tid - 200) * 8];
                *(float4*)dst       = make_float4(bf2f(pst[0]), bf2f(pst[1]), bf2f(pst[2]), bf2f(pst[3]));
                *(float4*)(dst + 4) = make_float4(bf2f(pst[4]), bf2f(pst[5]), bf2f(pst[6]), bf2f(pst[7]));
            }
            buf ^= 1;
        }
        __syncthreads();                        // chunk boundary: full fence
    }

    // epilogue t = TT: h2(199) from c_bf[0] = [o1(199) | h2(198)]
    if (l2t) {
        float a0 = (p3 == 0) ? b1 : 0.f;
        float a1 = 0.f, a2 = 0.f, a3 = 0.f;
        const unsigned short* cb = &c_bf[0][p3 * 56];
        const uint4 u0 = *(const uint4*)(cb +  0);
        const uint4 u1 = *(const uint4*)(cb +  8);
        const uint4 u2 = *(const uint4*)(cb + 16);
        const uint4 u3 = *(const uint4*)(cb + 24);
        const uint4 u4 = *(const uint4*)(cb + 32);
        const uint4 u5 = *(const uint4*)(cb + 40);
        const uint4 u6 = *(const uint4*)(cb + 48);
        const uint4 u7 = *(const uint4*)(cb + 56);
        UFMA(w00, u0.x, u0.y); UFMA(w01, u0.z, u0.w);
        UFMA(w02, u1.x, u1.y); UFMA(w03, u1.z, u1.w);
        UFMA(w04, u2.x, u2.y); UFMA(w05, u2.z, u2.w);
        UFMA(w06, u3.x, u3.y); UFMA(w07, u3.z, u3.w);
        UFMA(w08, u4.x, u4.y); UFMA(w09, u4.z, u4.w);
        UFMA(w10, u5.x, u5.y); UFMA(w11, u5.z, u5.w);
        UFMA(w12, u6.x, u6.y); UFMA(w13, u6.z, u6.w);
        UFMA(w14, u7.x, u7.y); UFMA(w15, u7.z, u7.w);
        float part = (a0 + a1) + (a2 + a3);
        part += __shfl_xor(part, 1);
        if (p3 == 0) h2f_s[k2] = fmaxf(part, 0.f);           // h2(199), f32
    }
    __syncthreads();

    if (tid < NO) {
        const float* m2 = mask2 + ((size_t)b * TT + (TT - 1)) * H2;
        float s = bfc[tid];
        #pragma unroll
        for (int k = 0; k < H2; ++k)
            s = fmaf(Wfc[tid * H2 + k], h2f_s[k] * m2[k], s);
        out[b * NO + tid] = s;
    }
}

extern "C" void kernel_launch(void* const* d_in, const int* in_sizes, int n_in,
                              void* d_out, int out_size, void* d_ws, size_t ws_size,
                              hipStream_t stream) {
    const float* x     = (const float*)d_in[0];
    const float* Wih1  = (const float*)d_in[1];
    const float* Whh1  = (const float*)d_in[2];
    const float* bih1  = (const float*)d_in[3];
    const float* bhh1  = (const float*)d_in[4];
    const float* Wih2  = (const float*)d_in[5];
    const float* Whh2  = (const float*)d_in[6];
    const float* bih2  = (const float*)d_in[7];
    const float* bhh2  = (const float*)d_in[8];
    const float* Wfc   = (const float*)d_in[9];
    const float* bfc   = (const float*)d_in[10];
    const float* mask1 = (const float*)d_in[11];
    const float* mask2 = (const float*)d_in[12];
    float* out = (float*)d_out;

    unsigned short* preT = (unsigned short*)d_ws;                     // 10,240,000 B
    unsigned short* w_ws = (unsigned short*)((char*)d_ws + 10240000); //    286,720 B

    prep_w  <<<dim3((WR * KPAD / 4 + 255) / 256), dim3(256), 0, stream>>>(Wih1, w_ws);
    gemm_pre<<<dim3(GRID_A), dim3(256), 0, stream>>>(x, w_ws, preT);
    scan_rnn<<<dim3(NB), dim3(320), 0, stream>>>(preT, Whh1, bih1, bhh1,
                                                 Wih2, Whh2, bih2, bhh2,
                                                 Wfc, bfc, mask1, mask2, out);
}

// Round 22
// 170.181 us; speedup vs baseline: 1.3216x; 1.0454x over previous
//
#include <hip/hip_runtime.h>

#define NB 256      // batch
#define TT 200      // time steps
#define DD 1250     // input dim
#define H1 100
#define H2 20
#define NO 2

// ---- GEMM kernel geometry ----
#define BM 64
#define GRID_A (51200 / BM)   // 800
#define KC 64
#define NCH 20                // 1280 / 64
#define WR 112
#define KPAD 1280

// ---- scan geometry ----
#define CH 8                  // steps per staged chunk
#define NCHK 25               // 200 / 8

typedef __attribute__((ext_vector_type(4))) float f32x4;
typedef __attribute__((ext_vector_type(8))) short s16x8;

__device__ __forceinline__ unsigned short f2bf(float f) {
    unsigned u = __builtin_bit_cast(unsigned, f);
    u += 0x7FFFu + ((u >> 16) & 1u);          // round-to-nearest-even
    return (unsigned short)(u >> 16);
}
__device__ __forceinline__ float bf2f(unsigned short s) {
    unsigned u = ((unsigned)s) << 16;
    return __builtin_bit_cast(float, u);
}

#define GLL(srcp, dstp) __builtin_amdgcn_global_load_lds( \
    (const __attribute__((address_space(1))) void*)(srcp), \
    (__attribute__((address_space(3))) void*)(dstp), 16, 0, 0)

// LDS-only barrier (r18-proven, scan): global loads stay in flight.
#define STEP_BARRIER() do {                                             \
    asm volatile("s_waitcnt lgkmcnt(0)\n\ts_barrier" ::: "memory");     \
    __builtin_amdgcn_sched_barrier(0);                                  \
} while (0)

// Counted-vmcnt barrier (T4): allow the newest 4 gll (= A(kc+2)) to stay
// in flight across the barrier; everything older (A(kc+1), W(kc+1)) drains.
#define BARRIER_V4() do {                                               \
    asm volatile("s_waitcnt vmcnt(4) lgkmcnt(0)\n\ts_barrier" ::: "memory"); \
    __builtin_amdgcn_sched_barrier(0);                                  \
} while (0)
#define BARRIER_V0() do {                                               \
    asm volatile("s_waitcnt vmcnt(0) lgkmcnt(0)\n\ts_barrier" ::: "memory"); \
    __builtin_amdgcn_sched_barrier(0);                                  \
} while (0)

// ============ kernel 0: Wih1 fp32 -> bf16 [112][1280] (padded) ===============
__global__ void prep_w(const float* __restrict__ Wih1, unsigned short* __restrict__ w_ws)
{
    const int idx = blockIdx.x * 256 + threadIdx.x;
    if (idx >= WR * KPAD / 4) return;
    const int r  = idx / (KPAD / 4);
    const int k4 = (idx - r * (KPAD / 4)) * 4;
    unsigned short o[4];
    #pragma unroll
    for (int e = 0; e < 4; ++e) {
        const int k = k4 + e;
        o[e] = (r < H1 && k < DD) ? f2bf(Wih1[r * DD + k]) : (unsigned short)0;
    }
    uint2 pk;
    pk.x = (unsigned)o[0] | ((unsigned)o[1] << 16);
    pk.y = (unsigned)o[2] | ((unsigned)o[3] << 16);
    *(uint2*)&w_ws[r * KPAD + k4] = pk;
}

// ============ kernel 1: pre1[(b*TT+t)*H1 + h] (bf16) — deep-pipelined ========
// r21 analysis: gemm at 4.4 TB/s because every __syncthreads drains vmcnt(0),
// so A-loads get only ~1 chunk (~400cy) of flight vs ~900cy HBM. Now: A is
// TRIPLE-buffered and issued 2 chunks ahead; per-chunk barrier is
// s_waitcnt vmcnt(4) (newest 4 = A(kc+2) stay in flight). W stays 2-buf,
// 1 ahead (L2-hot). kc=18 drains fully (no A follows); tail chunk 19 via
// guarded register loads + swizzled ds_write (r16-proven).
__launch_bounds__(256, 4)
__global__ void gemm_pre(const float* __restrict__ x,
                         const unsigned short* __restrict__ w_ws,
                         unsigned short* __restrict__ preT)
{
    __shared__ __align__(16) float          a_sf[3][BM * 64];   // 49152 B
    __shared__ __align__(16) unsigned short w_sh[2][WR * 64];   // 28672 B

    const int tid = threadIdx.x;
    const int bid = blockIdx.x;
    const int wv  = tid >> 6;
    const int ln  = tid & 63;
    const int c16 = ln & 15;
    const int kgrp = ln >> 4;

    f32x4 acc[7];
    #pragma unroll
    for (int i = 0; i < 7; ++i)
        #pragma unroll
        for (int c = 0; c < 4; ++c) acc[i][c] = 0.f;

    auto agll = [&](int k0, int buf) {
        #pragma unroll
        for (int q = 0; q < 4; ++q) {
            const int idx  = tid + q * 256;
            const int row  = idx >> 4;
            const int segp = idx & 15;
            const int segl = segp ^ (row & 15);            // inverse swizzle
            const float* src = x + (size_t)(bid * BM + row) * DD + k0 + segl * 4;
            GLL(src, &a_sf[buf][idx * 4]);
        }
    };
    auto wgll = [&](int k0, int buf) {
        #pragma unroll
        for (int q = 0; q < 4; ++q) {
            const int idx = tid + q * 256;
            if (idx < WR * 8) {
                const int row = idx >> 3;
                const int c8p = idx & 7;
                const int c8l = c8p ^ (row & 7);           // inverse swizzle
                const unsigned short* src = w_ws + row * KPAD + k0 + c8l * 8;
                GLL(src, &w_sh[buf][idx * 8]);
            }
        }
    };

    auto mfma_chunk = [&](int abuf, int wbuf) {
        #pragma unroll
        for (int s = 0; s < 2; ++s) {
            const int row_a = wv * 16 + c16;
            const int sb = s * 8 + kgrp * 2;
            const int sp0 = (sb + 0) ^ (row_a & 15);
            const int sp1 = (sb + 1) ^ (row_a & 15);
            const float4 av0 = *(const float4*)&a_sf[abuf][row_a * 64 + sp0 * 4];
            const float4 av1 = *(const float4*)&a_sf[abuf][row_a * 64 + sp1 * 4];
            const s16x8 af = {
                (short)f2bf(av0.x), (short)f2bf(av0.y),
                (short)f2bf(av0.z), (short)f2bf(av0.w),
                (short)f2bf(av1.x), (short)f2bf(av1.y),
                (short)f2bf(av1.z), (short)f2bf(av1.w) };
            #pragma unroll
            for (int nt = 0; nt < 7; ++nt) {
                const int row_b = nt * 16 + c16;
                const int c8  = s * 4 + kgrp;
                const int c8p = c8 ^ (row_b & 7);
                const s16x8 bf = *(const s16x8*)&w_sh[wbuf][row_b * 64 + c8p * 8];
                acc[nt] = __builtin_amdgcn_mfma_f32_16x16x32_bf16(af, bf, acc[nt], 0, 0, 0);
            }
        }
    };

    // tail chunk 19 (k 1216..1279, valid < 1250): guarded register loads
    float4 ta[4];
    #pragma unroll
    for (int q = 0; q < 4; ++q) {
        const int idx  = tid + q * 256;
        const int row  = idx >> 4;
        const int segl = idx & 15;
        const int gk   = 19 * KC + segl * 4;
        const float* xp = x + (size_t)(bid * BM + row) * DD + gk;
        float4 v;
        v.x = (gk + 0 < DD) ? xp[0] : 0.f;
        v.y = (gk + 1 < DD) ? xp[1] : 0.f;
        v.z = (gk + 2 < DD) ? xp[2] : 0.f;
        v.w = (gk + 3 < DD) ? xp[3] : 0.f;
        ta[q] = v;
    }

    // prologue: A0 -> buf0, W0 -> wbuf0, A1 -> buf1 (A1 rides across barrier)
    agll(0, 0);
    wgll(0, 0);
    agll(KC, 1);

    for (int kc = 0; kc < 19; ++kc) {
        // per-wave accounting: newest 4 gll = A(kc+1) [prologue: A1]; all
        // older (A(kc), W(kc)) must drain -> vmcnt(4). kc=18: W(18) is among
        // the newest 4 (no A was issued at kc=17), so drain fully.
        if (kc < 18) BARRIER_V4(); else BARRIER_V0();

        if (kc + 1 < NCH) wgll((kc + 1) * KC, (kc + 1) & 1);   // W 1 ahead
        if (kc + 2 < 19)  agll((kc + 2) * KC, (kc + 2) % 3);   // A 2 ahead

        mfma_chunk(kc % 3, kc & 1);
    }

    // tail: A via swizzled ds_write into buf 19%3==1 (consumed at kc=16)
    __syncthreads();                           // drain W(19) gll + all ds reads
    #pragma unroll
    for (int q = 0; q < 4; ++q) {
        const int idx  = tid + q * 256;
        const int row  = idx >> 4;
        const int segl = idx & 15;
        const int sp   = segl ^ (row & 15);
        *(float4*)&a_sf[1][row * 64 + sp * 4] = ta[q];
    }
    __syncthreads();                           // publishes A-tail
    mfma_chunk(1, 1);                          // chunk 19: wbuf = 19&1 = 1

    // C/D layout: col = l&15, row = (l>>4)*4 + reg  (m89-verified)
    const int rg = bid * BM + wv * 16 + (kgrp << 2);
    #pragma unroll
    for (int nt = 0; nt < 7; ++nt) {
        const int col = nt * 16 + c16;
        if (col < H1) {
            #pragma unroll
            for (int r = 0; r < 4; ++r)
                preT[(size_t)(rg + r) * H1 + col] = f2bf(acc[nt][r]);
        }
    }
}

// ============ kernel 2: fused two-layer scan + FC (r18 exact, proven) ========
#define FMA4(W, PTR) { const float4 hv_ = *(const float4*)(PTR);            \
    a0 = fmaf((W).x, hv_.x, a0); a1 = fmaf((W).y, hv_.y, a1);               \
    a2 = fmaf((W).z, hv_.z, a2); a3 = fmaf((W).w, hv_.w, a3); }

__launch_bounds__(320, 1)
__global__ void scan_rnn(const unsigned short* __restrict__ preT,
                         const float* __restrict__ Whh1,
                         const float* __restrict__ bih1,
                         const float* __restrict__ bhh1,
                         const float* __restrict__ Wih2,
                         const float* __restrict__ Whh2,
                         const float* __restrict__ bih2,
                         const float* __restrict__ bhh2,
                         const float* __restrict__ Wfc,
                         const float* __restrict__ bfc,
                         const float* __restrict__ mask1,
                         const float* __restrict__ mask2,
                         float* __restrict__ out)
{
    __shared__ alignas(16) float h1_s[2][104];    // [100..103] zero pad
    __shared__ alignas(16) float c_s[2][120];     // [0..99]=o1, [100..119]=h2
    __shared__ alignas(16) float h2f_s[H2];
    __shared__ alignas(16) float m_lds[2][CH * H1];   // mask1 chunks (f32)
    __shared__ alignas(16) float p_lds[2][CH * H1];   // pre1 chunks (f32)

    const int tid = threadIdx.x;
    const int b   = blockIdx.x;
    const float* m1b = mask1 + (size_t)b * TT * H1;
    const unsigned short* pTb = preT + (size_t)b * TT * H1;   // row-major [t][h]

    const int h = tid >> 1;
    const int p = tid & 1;
    const bool l1t = (tid < 200);
    const bool l2t = (tid >= 256 && tid < 256 + 2 * H2);   // wave 4 only
    const int k2 = (tid - 256) >> 1;
    const int p3 = (tid - 256) & 1;

    float4 w00{}, w01{}, w02{}, w03{}, w04{}, w05{}, w06{}, w07{},
           w08{}, w09{}, w10{}, w11{}, w12{}, w13{}, w14{};
    float b1 = 0.f, b2 = 0.f;

    if (l1t) {
        const float* wr = Whh1 + h * H1 + p * 52;
        w00 = *(const float4*)(wr +  0); w01 = *(const float4*)(wr +  4);
        w02 = *(const float4*)(wr +  8); w03 = *(const float4*)(wr + 12);
        w04 = *(const float4*)(wr + 16); w05 = *(const float4*)(wr + 20);
        w06 = *(const float4*)(wr + 24); w07 = *(const float4*)(wr + 28);
        w08 = *(const float4*)(wr + 32); w09 = *(const float4*)(wr + 36);
        w10 = *(const float4*)(wr + 40); w11 = *(const float4*)(wr + 44);
        if (p == 0) { w12 = *(const float4*)(wr + 48); b1 = bih1[h] + bhh1[h]; }
    } else if (l2t) {
        if (p3 == 0) {
            const float* wr = Wih2 + k2 * H1;           // [0..59]
            w00 = *(const float4*)(wr +  0); w01 = *(const float4*)(wr +  4);
            w02 = *(const float4*)(wr +  8); w03 = *(const float4*)(wr + 12);
            w04 = *(const float4*)(wr + 16); w05 = *(const float4*)(wr + 20);
            w06 = *(const float4*)(wr + 24); w07 = *(const float4*)(wr + 28);
            w08 = *(const float4*)(wr + 32); w09 = *(const float4*)(wr + 36);
            w10 = *(const float4*)(wr + 40); w11 = *(const float4*)(wr + 44);
            w12 = *(const float4*)(wr + 48); w13 = *(const float4*)(wr + 52);
            w14 = *(const float4*)(wr + 56);
            b2 = bih2[k2] + bhh2[k2];
        } else {
            const float* wr = Wih2 + k2 * H1 + 60;      // [60..99]
            w00 = *(const float4*)(wr +  0); w01 = *(const float4*)(wr +  4);
            w02 = *(const float4*)(wr +  8); w03 = *(const float4*)(wr + 12);
            w04 = *(const float4*)(wr + 16); w05 = *(const float4*)(wr + 20);
            w06 = *(const float4*)(wr + 24); w07 = *(const float4*)(wr + 28);
            w08 = *(const float4*)(wr + 32); w09 = *(const float4*)(wr + 36);
            const float* wh = Whh2 + k2 * H2;           // h2 part [100..119]
            w10 = *(const float4*)(wh +  0); w11 = *(const float4*)(wh +  4);
            w12 = *(const float4*)(wh +  8); w13 = *(const float4*)(wh + 12);
            w14 = *(const float4*)(wh + 16);
        }
    }

    for (int i = tid; i < 104; i += 320) { h1_s[0][i] = 0.f; h1_s[1][i] = 0.f; }
    for (int i = tid; i < 120; i += 320) { c_s[0][i] = 0.f; c_s[1][i] = 0.f; }

    // stage chunk 0 into buffer 0 (t = 0..7): one wide load per thread
    if (tid < 200) {
        const float4 mv = *(const float4*)&m1b[tid * 4];
        *(float4*)&m_lds[0][tid * 4] = mv;
    } else if (tid < 300) {
        const s16x8 pv = *(const s16x8*)&pTb[(tid - 200) * 8];
        float* dst = &p_lds[0][(tid - 200) * 8];
        *(float4*)dst       = make_float4(bf2f(pv[0]), bf2f(pv[1]), bf2f(pv[2]), bf2f(pv[3]));
        *(float4*)(dst + 4) = make_float4(bf2f(pv[4]), bf2f(pv[5]), bf2f(pv[6]), bf2f(pv[7]));
    }
    __syncthreads();

    int buf = 0;
    for (int c = 0; c < NCHK; ++c) {
        const bool more = (c + 1 < NCHK);
        float4 mst{}; s16x8 pst{};

        #pragma unroll
        for (int u = 0; u < CH; ++u) {
            const int t = c * CH + u;
            const int cur = t & 1, nxt = cur ^ 1;

            if (u > 0) STEP_BARRIER();         // LDS-only sync; no vmcnt drain

            if (u == 0 && more) {              // issue next chunk's loads
                const int base = (c + 1) * (CH * H1);
                if (tid < 200)      mst = *(const float4*)&m1b[base + tid * 4];
                else if (tid < 300) pst = *(const s16x8*)&pTb[base + (tid - 200) * 8];
            }

            if (l1t) {
                float a0 = (p == 0) ? (p_lds[buf][u * H1 + h] + b1) : 0.f;
                const float mv = (p == 1) ? m_lds[buf][u * H1 + h] : 0.f;
                float a1 = 0.f, a2 = 0.f, a3 = 0.f;
                const float* hb = &h1_s[cur][p * 52];
                FMA4(w00, hb +  0); FMA4(w01, hb +  4); FMA4(w02, hb +  8);
                FMA4(w03, hb + 12); FMA4(w04, hb + 16); FMA4(w05, hb + 20);
                FMA4(w06, hb + 24); FMA4(w07, hb + 28); FMA4(w08, hb + 32);
                FMA4(w09, hb + 36); FMA4(w10, hb + 40); FMA4(w11, hb + 44);
                FMA4(w12, hb + 48);
                float part = (a0 + a1) + (a2 + a3);
                float tot  = part + __shfl_xor(part, 1);
                tot = fmaxf(tot, 0.f);                       // h1(t)
                if (p == 0) h1_s[nxt][h] = tot;
                else        c_s[nxt][h] = tot * mv;          // o1(t)
            }

            if (l2t && t >= 1) {
                float a0 = (p3 == 0) ? b2 : 0.f;
                float a1 = 0.f, a2 = 0.f, a3 = 0.f;
                const float* cb = &c_s[cur][p3 * 60];
                FMA4(w00, cb +  0); FMA4(w01, cb +  4); FMA4(w02, cb +  8);
                FMA4(w03, cb + 12); FMA4(w04, cb + 16); FMA4(w05, cb + 20);
                FMA4(w06, cb + 24); FMA4(w07, cb + 28); FMA4(w08, cb + 32);
                FMA4(w09, cb + 36); FMA4(w10, cb + 40); FMA4(w11, cb + 44);
                FMA4(w12, cb + 48); FMA4(w13, cb + 52); FMA4(w14, cb + 56);
                float part = (a0 + a1) + (a2 + a3);
                part += __shfl_xor(part, 1);
                const float h2v = fmaxf(part, 0.f);          // h2(t-1)
                if (p3 == 0) c_s[nxt][100 + k2] = h2v;
            }
        }

        if (more) {                            // publish staged chunk
            if (tid < 200) {
                *(float4*)&m_lds[buf ^ 1][tid * 4] = mst;
            } else if (tid < 300) {
                float* dst = &p_lds[buf ^ 1][(tid - 200) * 8];
                *(float4*)dst       = make_float4(bf2f(pst[0]), bf2f(pst[1]), bf2f(pst[2]), bf2f(pst[3]));
                *(float4*)(dst + 4) = make_float4(bf2f(pst[4]), bf2f(pst[5]), bf2f(pst[6]), bf2f(pst[7]));
            }
            buf ^= 1;
        }
        __syncthreads();                        // chunk boundary: full fence
    }

    // epilogue t = TT: layer2 computes h2(199) from o1(199), h2(198)
    {
        const int cur = TT & 1;                              // 0
        if (l2t) {
            float a0 = (p3 == 0) ? b2 : 0.f;
            float a1 = 0.f, a2 = 0.f, a3 = 0.f;
            const float* cb = &c_s[cur][p3 * 60];
            FMA4(w00, cb +  0); FMA4(w01, cb +  4); FMA4(w02, cb +  8);
            FMA4(w03, cb + 12); FMA4(w04, cb + 16); FMA4(w05, cb + 20);
            FMA4(w06, cb + 24); FMA4(w07, cb + 28); FMA4(w08, cb + 32);
            FMA4(w09, cb + 36); FMA4(w10, cb + 40); FMA4(w11, cb + 44);
            FMA4(w12, cb + 48); FMA4(w13, cb + 52); FMA4(w14, cb + 56);
            float part = (a0 + a1) + (a2 + a3);
            part += __shfl_xor(part, 1);
            if (p3 == 0) h2f_s[k2] = fmaxf(part, 0.f);       // h2(199)
        }
        __syncthreads();
    }

    if (tid < NO) {
        const float* m2 = mask2 + ((size_t)b * TT + (TT - 1)) * H2;
        float s = bfc[tid];
        #pragma unroll
        for (int k = 0; k < H2; ++k)
            s = fmaf(Wfc[tid * H2 + k], h2f_s[k] * m2[k], s);
        out[b * NO + tid] = s;
    }
}

extern "C" void kernel_launch(void* const* d_in, const int* in_sizes, int n_in,
                              void* d_out, int out_size, void* d_ws, size_t ws_size,
                              hipStream_t stream) {
    const float* x     = (const float*)d_in[0];
    const float* Wih1  = (const float*)d_in[1];
    const float* Whh1  = (const float*)d_in[2];
    const float* bih1  = (const float*)d_in[3];
    const float* bhh1  = (const float*)d_in[4];
    const float* Wih2  = (const float*)d_in[5];
    const float* Whh2  = (const float*)d_in[6];
    const float* bih2  = (const float*)d_in[7];
    const float* bhh2  = (const float*)d_in[8];
    const float* Wfc   = (const float*)d_in[9];
    const float* bfc   = (const float*)d_in[10];
    const float* mask1 = (const float*)d_in[11];
    const float* mask2 = (const float*)d_in[12];
    float* out = (float*)d_out;

    unsigned short* preT = (unsigned short*)d_ws;                     // 10,240,000 B
    unsigned short* w_ws = (unsigned short*)((char*)d_ws + 10240000); //    286,720 B

    prep_w  <<<dim3((WR * KPAD / 4 + 255) / 256), dim3(256), 0, stream>>>(Wih1, w_ws);
    gemm_pre<<<dim3(GRID_A), dim3(256), 0, stream>>>(x, w_ws, preT);
    scan_rnn<<<dim3(NB), dim3(320), 0, stream>>>(preT, Whh1, bih1, bhh1,
                                                 Wih2, Whh2, bih2, bhh2,
                                                 Wfc, bfc, mask1, mask2, out);
}